// Round 1
// baseline (378.358 us; speedup 1.0000x reference)
//
#include <hip/hip_runtime.h>

// GraphSelfAttention: E3NN-style graph attention, fused per-edge kernel.
// Sizes: N=20000 nodes, E=120000 edges, MUL0=16, MUL1=8, NB=10, DK=16, DV=32.

#define MUL0 16
#define MUL1 8
#define NBASIS 10
#define DK 16
#define DV 32
#define XDIM 40   // MUL0 + 3*MUL1

// CC = 1.14136 * e^2 * sqrt(10)
#define CC 26.6692987f
// 1/sqrt(10)
#define INV_SQRT10 0.3162277660f
// 1/(sqrt(16)*sqrt(MUL0+MUL1)) = 1/(4*sqrt(24))
#define KV_SCALE 0.0510310363f

__global__ void node_qd_kernel(const float* __restrict__ x,
                               const float* __restrict__ Wq,
                               const float* __restrict__ Wdot,
                               float* __restrict__ qd, int N) {
    int n = blockIdx.x * blockDim.x + threadIdx.x;
    if (n >= N) return;
    const float* xr = x + (size_t)n * XDIM;
    float x0[MUL0];
#pragma unroll
    for (int u = 0; u < MUL0; ++u) x0[u] = xr[u];
    float q[DK];
#pragma unroll
    for (int w = 0; w < DK; ++w) {
        float a = 0.f;
#pragma unroll
        for (int u = 0; u < MUL0; ++u) a += x0[u] * Wq[u * DK + w];
        q[w] = a * 0.25f;  // /sqrt(16)
    }
#pragma unroll
    for (int w = 0; w < DK; ++w) {
        float a = 0.f;
#pragma unroll
        for (int u = 0; u < DK; ++u) a += q[u] * Wdot[u * DK + w];
        qd[(size_t)n * DK + w] = a * 0.0625f;  // /MUL0
    }
}

__global__ __launch_bounds__(256) void edge_kernel(
    const float* __restrict__ x, const float* __restrict__ pos,
    const float* __restrict__ Wk1, const float* __restrict__ Wk2,
    const float* __restrict__ Wv1, const float* __restrict__ Wv2,
    const float* __restrict__ qd,
    const int* __restrict__ esrc, const int* __restrict__ edst,
    float* __restrict__ zbuf, float* __restrict__ expvbuf,
    float* __restrict__ vbuf, int E) {
    int e = blockIdx.x * blockDim.x + threadIdx.x;
    if (e >= E) return;
    int s = esrc[e];
    int d = edst[e];

    float ev0 = pos[s * 3 + 0] - pos[d * 3 + 0];
    float ev1 = pos[s * 3 + 1] - pos[d * 3 + 1];
    float ev2 = pos[s * 3 + 2] - pos[d * 3 + 2];
    float len2 = ev0 * ev0 + ev1 * ev1 + ev2 * ev2 + 1e-12f;
    float elen = sqrtf(len2);
    float inv = 1.0f / elen;

    // radial basis: emb_i = CC * sus(t - i) * sus(i+2 - t), t = elen/step
    float t = elen * 2.75f;  // 11/4
    float emb[NBASIS];
#pragma unroll
    for (int i = 0; i < NBASIS; ++i) {
        float a = t - (float)i;
        float b = (float)(i + 2) - t;
        emb[i] = (a > 0.f && b > 0.f) ? CC * expf(-1.f / a - 1.f / b) : 0.f;
    }

    // h_k, h_v = silu(emb @ W1 / sqrt(10))
    float hk[16], hv[16];
#pragma unroll
    for (int j = 0; j < 16; ++j) {
        float ak = 0.f, av = 0.f;
#pragma unroll
        for (int i = 0; i < NBASIS; ++i) {
            ak += emb[i] * Wk1[i * 16 + j];
            av += emb[i] * Wv1[i * 16 + j];
        }
        ak *= INV_SQRT10;
        av *= INV_SQRT10;
        hk[j] = ak / (1.f + expf(-ak));
        hv[j] = av / (1.f + expf(-av));
    }

    // f = [x0_src (16), x1dot (8)]
    float f[24];
    const float* xr = x + (size_t)s * XDIM;
#pragma unroll
    for (int u = 0; u < MUL0; ++u) f[u] = xr[u];
#pragma unroll
    for (int u = 0; u < MUL1; ++u) {
        f[MUL0 + u] = (xr[16 + u * 3 + 0] * ev0 + xr[16 + u * 3 + 1] * ev1 +
                       xr[16 + u * 3 + 2] * ev2) * inv;
    }

    // k[w] = scale * sum_{c,u} hk[c] * Wk2[c, u*16+w] * f[u]   (u in 0..23)
    // v[w] = scale * sum_{c,u} hv[c] * Wv2[c, u*32+w] * f[u]
    float kk[DK];
    float vv[DV];
#pragma unroll
    for (int w = 0; w < DK; ++w) kk[w] = 0.f;
#pragma unroll
    for (int w = 0; w < DV; ++w) vv[w] = 0.f;

    for (int c = 0; c < 16; ++c) {  // wave-uniform loop -> scalar weight loads
        float tk = hk[c];
        float tv = hv[c];
        const float* __restrict__ wkrow = Wk2 + c * 384;
        const float* __restrict__ wvrow = Wv2 + c * 768;
#pragma unroll
        for (int u = 0; u < 24; ++u) {
            float gk = tk * f[u];
            float gv = tv * f[u];
#pragma unroll
            for (int w = 0; w < DK; ++w) kk[w] += gk * wkrow[u * 16 + w];
#pragma unroll
            for (int w = 0; w < DV; ++w) vv[w] += gv * wvrow[u * 32 + w];
        }
    }

    // logits = dot(qd[dst], k)
    const float* qdr = qd + (size_t)d * DK;
    float logit = 0.f;
#pragma unroll
    for (int w = 0; w < DK; ++w) logit += qdr[w] * kk[w];
    logit *= KV_SCALE;

    float arg = 10.f - 2.5f * elen;  // 10*(1 - elen/RMAX)
    float wcut = (arg > 0.f) ? expf(-1.f / arg) : 0.f;
    float expv = wcut * expf(logit);

    expvbuf[e] = expv;
    if (expv != 0.f) atomicAdd(&zbuf[d], expv);

    float* vr = vbuf + (size_t)e * DV;
#pragma unroll
    for (int w = 0; w < DV; ++w) vr[w] = vv[w] * KV_SCALE;
}

__global__ void scatter_kernel(const float* __restrict__ expvbuf,
                               const float* __restrict__ vbuf,
                               const float* __restrict__ zbuf,
                               const int* __restrict__ edst,
                               float* __restrict__ out, int E) {
    int e = blockIdx.x * blockDim.x + threadIdx.x;
    if (e >= E) return;
    float expv = expvbuf[e];
    if (expv == 0.f) return;
    int d = edst[e];
    float z = zbuf[d];  // z >= expv > 0
    float salpha = sqrtf(expv / z);
    const float* vr = vbuf + (size_t)e * DV;
#pragma unroll
    for (int w = 0; w < DV; ++w) {
        atomicAdd(&out[(size_t)d * DV + w], salpha * vr[w]);
    }
}

extern "C" void kernel_launch(void* const* d_in, const int* in_sizes, int n_in,
                              void* d_out, int out_size, void* d_ws, size_t ws_size,
                              hipStream_t stream) {
    const float* x    = (const float*)d_in[0];
    const float* pos  = (const float*)d_in[1];
    const float* Wq   = (const float*)d_in[2];
    const float* Wk1  = (const float*)d_in[3];
    const float* Wk2  = (const float*)d_in[4];
    const float* Wv1  = (const float*)d_in[5];
    const float* Wv2  = (const float*)d_in[6];
    const float* Wdot = (const float*)d_in[7];
    const int* esrc   = (const int*)d_in[8];
    const int* edst   = (const int*)d_in[9];

    const int N = in_sizes[0] / XDIM;
    const int E = in_sizes[8];

    float* out = (float*)d_out;

    // workspace layout
    float* qd      = (float*)d_ws;            // N*16
    float* zbuf    = qd + (size_t)N * DK;     // N
    float* expvbuf = zbuf + N;                // E
    float* vbuf    = expvbuf + E;             // E*32

    // zero accumulators (out is poisoned; z must start at 0 each call)
    hipMemsetAsync(out, 0, (size_t)out_size * sizeof(float), stream);
    hipMemsetAsync(zbuf, 0, (size_t)N * sizeof(float), stream);

    {
        int bs = 256, gs = (N + bs - 1) / bs;
        node_qd_kernel<<<gs, bs, 0, stream>>>(x, Wq, Wdot, qd, N);
    }
    {
        int bs = 256, gs = (E + bs - 1) / bs;
        edge_kernel<<<gs, bs, 0, stream>>>(x, pos, Wk1, Wk2, Wv1, Wv2, qd,
                                           esrc, edst, zbuf, expvbuf, vbuf, E);
    }
    {
        int bs = 256, gs = (E + bs - 1) / bs;
        scatter_kernel<<<gs, bs, 0, stream>>>(expvbuf, vbuf, zbuf, edst, out, E);
    }
}

// Round 2
// 230.035 us; speedup vs baseline: 1.6448x; 1.6448x over previous
//
#include <hip/hip_runtime.h>

// GraphSelfAttention: E3NN-style graph attention.
// N=20000 nodes, E=120000 edges, MUL0=16, MUL1=8, NB=10, DK=16, DV=32.
// Round 2: replace atomic scatter with CSR-bucketed gather (no atomics on out).

#define MUL0 16
#define MUL1 8
#define NBASIS 10
#define DK 16
#define DV 32
#define XDIM 40   // MUL0 + 3*MUL1

#define CC 26.6692987f          // 1.14136 * e^2 * sqrt(10)
#define INV_SQRT10 0.3162277660f
#define KV_SCALE 0.0510310363f  // 1/(4*sqrt(24))

__global__ void node_qd_kernel(const float* __restrict__ x,
                               const float* __restrict__ Wq,
                               const float* __restrict__ Wdot,
                               float* __restrict__ qd, int N) {
    int n = blockIdx.x * blockDim.x + threadIdx.x;
    if (n >= N) return;
    const float* xr = x + (size_t)n * XDIM;
    float x0[MUL0];
#pragma unroll
    for (int u = 0; u < MUL0; ++u) x0[u] = xr[u];
    float q[DK];
#pragma unroll
    for (int w = 0; w < DK; ++w) {
        float a = 0.f;
#pragma unroll
        for (int u = 0; u < MUL0; ++u) a += x0[u] * Wq[u * DK + w];
        q[w] = a * 0.25f;  // /sqrt(16)
    }
#pragma unroll
    for (int w = 0; w < DK; ++w) {
        float a = 0.f;
#pragma unroll
        for (int u = 0; u < DK; ++u) a += q[u] * Wdot[u * DK + w];
        qd[(size_t)n * DK + w] = a * 0.0625f;  // /MUL0
    }
}

__global__ __launch_bounds__(256) void edge_kernel(
    const float* __restrict__ x, const float* __restrict__ pos,
    const float* __restrict__ Wk1, const float* __restrict__ Wk2,
    const float* __restrict__ Wv1, const float* __restrict__ Wv2,
    const float* __restrict__ qd,
    const int* __restrict__ esrc, const int* __restrict__ edst,
    float* __restrict__ zbuf, float* __restrict__ expvbuf,
    float* __restrict__ vbuf, int* __restrict__ deg, int E) {
    int e = blockIdx.x * blockDim.x + threadIdx.x;
    if (e >= E) return;
    int s = esrc[e];
    int d = edst[e];

    atomicAdd(&deg[d], 1);  // histogram for CSR build (L2-resident ints)

    float ev0 = pos[s * 3 + 0] - pos[d * 3 + 0];
    float ev1 = pos[s * 3 + 1] - pos[d * 3 + 1];
    float ev2 = pos[s * 3 + 2] - pos[d * 3 + 2];
    float len2 = ev0 * ev0 + ev1 * ev1 + ev2 * ev2 + 1e-12f;
    float elen = sqrtf(len2);
    float inv = 1.0f / elen;

    // radial basis: emb_i = CC * sus(t - i) * sus(i+2 - t), t = elen/step
    float t = elen * 2.75f;
    float emb[NBASIS];
#pragma unroll
    for (int i = 0; i < NBASIS; ++i) {
        float a = t - (float)i;
        float b = (float)(i + 2) - t;
        emb[i] = (a > 0.f && b > 0.f) ? CC * expf(-1.f / a - 1.f / b) : 0.f;
    }

    // h_k, h_v = silu(emb @ W1 / sqrt(10))
    float hk[16], hv[16];
#pragma unroll
    for (int j = 0; j < 16; ++j) {
        float ak = 0.f, av = 0.f;
#pragma unroll
        for (int i = 0; i < NBASIS; ++i) {
            ak += emb[i] * Wk1[i * 16 + j];
            av += emb[i] * Wv1[i * 16 + j];
        }
        ak *= INV_SQRT10;
        av *= INV_SQRT10;
        hk[j] = ak / (1.f + expf(-ak));
        hv[j] = av / (1.f + expf(-av));
    }

    // f = [x0_src (16), x1dot (8)]
    float f[24];
    const float* xr = x + (size_t)s * XDIM;
#pragma unroll
    for (int u = 0; u < MUL0; ++u) f[u] = xr[u];
#pragma unroll
    for (int u = 0; u < MUL1; ++u) {
        f[MUL0 + u] = (xr[16 + u * 3 + 0] * ev0 + xr[16 + u * 3 + 1] * ev1 +
                       xr[16 + u * 3 + 2] * ev2) * inv;
    }

    float kk[DK];
    float vv[DV];
#pragma unroll
    for (int w = 0; w < DK; ++w) kk[w] = 0.f;
#pragma unroll
    for (int w = 0; w < DV; ++w) vv[w] = 0.f;

    for (int c = 0; c < 16; ++c) {  // wave-uniform loop -> scalar weight loads
        float tk = hk[c];
        float tv = hv[c];
        const float* __restrict__ wkrow = Wk2 + c * 384;
        const float* __restrict__ wvrow = Wv2 + c * 768;
#pragma unroll
        for (int u = 0; u < 24; ++u) {
            float gk = tk * f[u];
            float gv = tv * f[u];
#pragma unroll
            for (int w = 0; w < DK; ++w) kk[w] += gk * wkrow[u * 16 + w];
#pragma unroll
            for (int w = 0; w < DV; ++w) vv[w] += gv * wvrow[u * 32 + w];
        }
    }

    const float* qdr = qd + (size_t)d * DK;
    float logit = 0.f;
#pragma unroll
    for (int w = 0; w < DK; ++w) logit += qdr[w] * kk[w];
    logit *= KV_SCALE;

    float arg = 10.f - 2.5f * elen;  // 10*(1 - elen/RMAX)
    float wcut = (arg > 0.f) ? expf(-1.f / arg) : 0.f;
    float expv = wcut * expf(logit);

    expvbuf[e] = expv;
    if (expv != 0.f) atomicAdd(&zbuf[d], expv);

    float* vr = vbuf + (size_t)e * DV;
#pragma unroll
    for (int w = 0; w < DV; ++w) vr[w] = vv[w] * KV_SCALE;
}

// Single-block exclusive scan of deg[0..N) -> start[0..N], start[N] = total.
__global__ __launch_bounds__(1024) void scan_kernel(const int* __restrict__ deg,
                                                    int* __restrict__ start, int N) {
    __shared__ int lds[1024];
    const int tid = threadIdx.x;
    const int chunk = (N + 1023) / 1024;
    const int lo = tid * chunk;
    const int hi = min(N, lo + chunk);
    int s = 0;
    for (int i = lo; i < hi; ++i) s += deg[i];
    lds[tid] = s;
    __syncthreads();
    // Hillis-Steele inclusive scan over 1024 partials
    for (int off = 1; off < 1024; off <<= 1) {
        int v = (tid >= off) ? lds[tid - off] : 0;
        __syncthreads();
        lds[tid] += v;
        __syncthreads();
    }
    int running = lds[tid] - s;  // exclusive base for this chunk
    for (int i = lo; i < hi; ++i) {
        start[i] = running;
        running += deg[i];
    }
    if (tid == 1023) start[N] = lds[1023];
}

__global__ void fill_kernel(const int* __restrict__ edst,
                            const int* __restrict__ start,
                            int* __restrict__ cursor,
                            int* __restrict__ bucket, int E) {
    int e = blockIdx.x * blockDim.x + threadIdx.x;
    if (e >= E) return;
    int d = edst[e];
    int p = atomicAdd(&cursor[d], 1);
    bucket[start[d] + p] = e;
}

// 32 lanes per node, one lane per output column. No atomics.
__global__ __launch_bounds__(256) void gather_kernel(
    const float* __restrict__ expvbuf, const float* __restrict__ vbuf,
    const float* __restrict__ zbuf, const int* __restrict__ start,
    const int* __restrict__ bucket, float* __restrict__ out, int N) {
    int n = blockIdx.x * 8 + (threadIdx.x >> 5);
    int w = threadIdx.x & 31;
    if (n >= N) return;
    float z = zbuf[n];
    if (z == 0.f) z = 1.f;
    float rz = 1.0f / z;
    int lo = start[n], hi = start[n + 1];
    float acc = 0.f;
    for (int i = lo; i < hi; ++i) {
        int e = bucket[i];                 // broadcast across 32 lanes
        float ev = expvbuf[e];             // broadcast
        float sa = sqrtf(ev * rz);
        acc += sa * vbuf[(size_t)e * DV + w];  // coalesced across lanes
    }
    out[(size_t)n * DV + w] = acc;
}

extern "C" void kernel_launch(void* const* d_in, const int* in_sizes, int n_in,
                              void* d_out, int out_size, void* d_ws, size_t ws_size,
                              hipStream_t stream) {
    const float* x    = (const float*)d_in[0];
    const float* pos  = (const float*)d_in[1];
    const float* Wq   = (const float*)d_in[2];
    const float* Wk1  = (const float*)d_in[3];
    const float* Wk2  = (const float*)d_in[4];
    const float* Wv1  = (const float*)d_in[5];
    const float* Wv2  = (const float*)d_in[6];
    const float* Wdot = (const float*)d_in[7];
    const int* esrc   = (const int*)d_in[8];
    const int* edst   = (const int*)d_in[9];

    const int N = in_sizes[0] / XDIM;
    const int E = in_sizes[8];

    float* out = (float*)d_out;

    // workspace layout (all 4-byte elements)
    float* qd      = (float*)d_ws;              // N*16
    float* zbuf    = qd + (size_t)N * DK;       // N      } contiguous zero
    int*   deg     = (int*)(zbuf + N);          // N      } block: one
    int*   cursor  = deg + N;                   // N      } memset
    int*   start   = cursor + N;                // N+1
    int*   bucket  = start + N + 1;             // E
    float* expvbuf = (float*)(bucket + E);      // E
    float* vbuf    = expvbuf + E;               // E*32

    // zbuf, deg, cursor are contiguous: one memset (fp32 0.0 == int 0)
    hipMemsetAsync(zbuf, 0, (size_t)(3 * N) * sizeof(int), stream);

    {
        int bs = 256, gs = (N + bs - 1) / bs;
        node_qd_kernel<<<gs, bs, 0, stream>>>(x, Wq, Wdot, qd, N);
    }
    {
        int bs = 256, gs = (E + bs - 1) / bs;
        edge_kernel<<<gs, bs, 0, stream>>>(x, pos, Wk1, Wk2, Wv1, Wv2, qd,
                                           esrc, edst, zbuf, expvbuf, vbuf, deg, E);
    }
    scan_kernel<<<1, 1024, 0, stream>>>(deg, start, N);
    {
        int bs = 256, gs = (E + bs - 1) / bs;
        fill_kernel<<<gs, bs, 0, stream>>>(edst, start, cursor, bucket, E);
    }
    {
        int bs = 256, gs = (N + 7) / 8;
        gather_kernel<<<gs, bs, 0, stream>>>(expvbuf, vbuf, zbuf, start, bucket, out, N);
    }
}